// Round 1
// baseline (244.385 us; speedup 1.0000x reference)
//
#include <hip/hip_runtime.h>
#include <hip/hip_bf16.h>
#include <stdint.h>

// VectorQuantizer on MI355X (gfx950)
// inputs: x [64,256,32,32] fp32 (NCHW), codebook [1024,256] fp32
// outputs: q_st [64,256,32,32] fp32 (== codebook[argmin] scattered back), loss scalar
//
// Strategy: bf16 MFMA distance GEMM (argmin_k of norm_k - 2*x.c_k), A-frags in
// registers (no barriers in K-loop), B-frags from L2-resident bf16 codebook,
// fused gather + NCHW write + loss (loss = 1.25/ND * sum(||x||^2 + minval)).

#define DIM 256
#define KCODES 1024
#define BN 128         // rows per block
#define XT_STRIDE_W 132  // LDS words per row: 256 bf16 = 128 words, +4 pad (8-way write conflicts, b128-read aligned)

typedef __attribute__((ext_vector_type(8))) short bf16x8_t;   // 8 bf16 = 4 VGPRs (MFMA A/B frag)
typedef __attribute__((ext_vector_type(4))) float f32x4_t;    // MFMA C/D frag

__device__ __forceinline__ unsigned short f2bf(float f) {
    union { float f; uint32_t u; } v; v.f = f;
    uint32_t r = v.u + 0x7FFFu + ((v.u >> 16) & 1u);   // RNE
    return (unsigned short)(r >> 16);
}

// ---- kernel 0: cast codebook fp32 -> bf16 (packed u32 pairs) + row norms ----
// 1024 codes, one wave per code: grid 256 x 256 threads.
__global__ __launch_bounds__(256) void vq_prep(const float* __restrict__ cb,
                                               uint32_t* __restrict__ cb_bf,
                                               float* __restrict__ norms) {
    const int code = blockIdx.x * 4 + (threadIdx.x >> 6);
    const int lane = threadIdx.x & 63;
    const f32x4_t v = ((const f32x4_t*)(cb + code * DIM))[lane];
    float sq = v.x * v.x + v.y * v.y + v.z * v.z + v.w * v.w;
    uint32_t* orow = cb_bf + code * (DIM / 2);
    orow[lane * 2 + 0] = (uint32_t)f2bf(v.x) | ((uint32_t)f2bf(v.y) << 16);
    orow[lane * 2 + 1] = (uint32_t)f2bf(v.z) | ((uint32_t)f2bf(v.w) << 16);
    #pragma unroll
    for (int m = 32; m; m >>= 1) sq += __shfl_xor(sq, m, 64);
    if (lane == 0) norms[code] = sq;
}

// ---- kernel 1: main fused kernel ----
// grid 512 blocks x 256 threads; block handles 128 consecutive rows (same image).
__global__ __launch_bounds__(256) void vq_main(const float* __restrict__ x,
                                               const float* __restrict__ cb,
                                               const uint32_t* __restrict__ cb_bf,
                                               const float* __restrict__ norms,
                                               float* __restrict__ out,
                                               float* __restrict__ loss_accum) {
    __shared__ __align__(16) uint32_t xt[BN * XT_STRIDE_W];  // [row][d] bf16, 67.6 KB
    __shared__ float xsq_s[256];
    __shared__ float rowmin_s[BN];
    __shared__ int   rowidx_s[BN];

    const int t    = threadIdx.x;
    const int wave = t >> 6;
    const int lane = t & 63;
    const int quad = lane >> 4;
    const int n0   = blockIdx.x * BN;
    const int batch = n0 >> 10;        // 1024 hw positions per image
    const int hw0   = n0 & 1023;

    // ---- stage X: transpose NCHW -> LDS [row][d] bf16, accumulate ||x||^2 in fp32
    {
        const int nl = t & 127;        // local row
        const int ds = t >> 7;         // 0..1: which half of the d-pairs
        const float* xb = x + (size_t)batch * (DIM * 1024) + hw0 + nl;
        float sq = 0.f;
        #pragma unroll 8
        for (int p = 0; p < 64; ++p) {
            const int d = ds * 2 + p * 4;              // even; covers all even d once
            const float a0 = xb[(size_t)d * 1024];
            const float a1 = xb[(size_t)(d + 1) * 1024];
            sq += a0 * a0 + a1 * a1;
            xt[nl * XT_STRIDE_W + (d >> 1)] =
                (uint32_t)f2bf(a0) | ((uint32_t)f2bf(a1) << 16);
        }
        xsq_s[t] = sq;
    }
    __syncthreads();

    // ---- A-fragments in registers: 2 row-tiles x 8 k-steps
    // A layout: lane holds A[m = lane&15][k = quad*8 + j]
    bf16x8_t afrag[2][8];
    #pragma unroll
    for (int rt = 0; rt < 2; ++rt) {
        const int m = wave * 32 + rt * 16 + (lane & 15);
        #pragma unroll
        for (int s = 0; s < 8; ++s)
            afrag[rt][s] = *(const bf16x8_t*)((const char*)xt +
                                              m * (XT_STRIDE_W * 4) + s * 64 + quad * 16);
    }

    // ---- K-loop over 1024 codes: score = norm_k - 2 * dot(x, c_k)
    float minv[2][4];
    int   mini[2][4];
    #pragma unroll
    for (int rt = 0; rt < 2; ++rt)
        #pragma unroll
        for (int r = 0; r < 4; ++r) { minv[rt][r] = 3.0e38f; mini[rt][r] = 0; }

    const bf16x8_t* cb8 = (const bf16x8_t*)cb_bf;   // row stride = 32 frags

    for (int kt = 0; kt < 16; ++kt) {
        #pragma unroll
        for (int ct = 0; ct < 4; ++ct) {
            const int code = kt * 64 + ct * 16 + (lane & 15);
            f32x4_t acc0 = {0.f, 0.f, 0.f, 0.f};
            f32x4_t acc1 = {0.f, 0.f, 0.f, 0.f};
            #pragma unroll
            for (int s = 0; s < 8; ++s) {
                const bf16x8_t b = cb8[code * 32 + s * 4 + quad];  // B[n=lane&15][k=quad*8+j]
                acc0 = __builtin_amdgcn_mfma_f32_16x16x32_bf16(afrag[0][s], b, acc0, 0, 0, 0);
                acc1 = __builtin_amdgcn_mfma_f32_16x16x32_bf16(afrag[1][s], b, acc1, 0, 0, 0);
            }
            const float nrm = norms[code];
            #pragma unroll
            for (int r = 0; r < 4; ++r) {
                const float s0 = nrm - 2.f * acc0[r];
                if (s0 < minv[0][r]) { minv[0][r] = s0; mini[0][r] = code; }
                const float s1 = nrm - 2.f * acc1[r];
                if (s1 < minv[1][r]) { minv[1][r] = s1; mini[1][r] = code; }
            }
        }
    }

    // ---- argmin reduce across the 16 lanes sharing a row (C/D: col=lane&15, row=quad*4+reg)
    #pragma unroll
    for (int rt = 0; rt < 2; ++rt) {
        #pragma unroll
        for (int r = 0; r < 4; ++r) {
            float v = minv[rt][r];
            int  ix = mini[rt][r];
            #pragma unroll
            for (int m = 1; m < 16; m <<= 1) {
                const float ov = __shfl_xor(v, m, 64);
                const int   oi = __shfl_xor(ix, m, 64);
                if (ov < v || (ov == v && oi < ix)) { v = ov; ix = oi; }
            }
            if ((lane & 15) == 0) {
                const int rl = wave * 32 + rt * 16 + quad * 4 + r;
                rowmin_s[rl] = v;
                rowidx_s[rl] = ix;
            }
        }
    }
    __syncthreads();

    // ---- loss partial: sum over rows of (||x||^2 + minval); one atomic per wave (waves 0,1)
    if (t < 128) {
        float s = xsq_s[t] + xsq_s[t + 128] + rowmin_s[t];
        #pragma unroll
        for (int m = 32; m; m >>= 1) s += __shfl_xor(s, m, 64);
        if ((t & 63) == 0) atomicAdd(loss_accum, s);
    }

    // ---- gather chosen codebook rows (fp32) and scatter to NCHW output (coalesced along hw)
    {
        const int nl = t & 127;
        const int dg = t >> 7;
        const int code = rowidx_s[nl];
        const f32x4_t* crow = (const f32x4_t*)(cb + code * DIM);
        float* ob = out + (size_t)batch * (DIM * 1024) + hw0 + nl;
        #pragma unroll 4
        for (int j = 0; j < 32; ++j) {
            const int d0 = dg * 128 + j * 4;
            const f32x4_t c4 = crow[d0 >> 2];
            ob[(size_t)(d0 + 0) * 1024] = c4.x;
            ob[(size_t)(d0 + 1) * 1024] = c4.y;
            ob[(size_t)(d0 + 2) * 1024] = c4.z;
            ob[(size_t)(d0 + 3) * 1024] = c4.w;
        }
    }
}

// ---- kernel 2: finalize loss ----
__global__ void vq_final(const float* __restrict__ loss_accum, float* __restrict__ out_loss) {
    *out_loss = 1.25f * (*loss_accum) / 16777216.f;
}

extern "C" void kernel_launch(void* const* d_in, const int* in_sizes, int n_in,
                              void* d_out, int out_size, void* d_ws, size_t ws_size,
                              hipStream_t stream) {
    const float* x  = (const float*)d_in[0];   // [64,256,32,32]
    const float* cb = (const float*)d_in[1];   // [1024,256]
    float* out = (float*)d_out;                // 16777216 + 1

    char* ws = (char*)d_ws;
    float*    loss_accum = (float*)ws;                       // 4 B (zeroed below)
    uint32_t* cb_bf      = (uint32_t*)(ws + 1024);           // 512 KB bf16 codebook
    float*    norms      = (float*)(ws + 1024 + 512 * 1024); // 4 KB

    hipMemsetAsync(loss_accum, 0, sizeof(float), stream);
    vq_prep<<<dim3(KCODES / 4), dim3(256), 0, stream>>>(cb, cb_bf, norms);
    vq_main<<<dim3(65536 / BN), dim3(256), 0, stream>>>(x, cb, cb_bf, norms, out, loss_accum);
    vq_final<<<dim3(1), dim3(1), 0, stream>>>(loss_accum, out + 16777216);
}